// Round 11
// baseline (4799.125 us; speedup 1.0000x reference)
//
#include <hip/hip_runtime.h>
#include <math.h>

// NodeformerProcessor: 3x (nodeformer_conv -> [leaky] -> graph_norm).
// v9: = v8 with two targeted fixes.
//     - k_kv dd-loop: node-minor item mapping (dm wave-quasi-uniform) +
//       kplV[30][16] layout -> LDS bank conflicts ~0 (v8: 1.04e7 from
//       per-lane row indexing at pitch 68).
//     - k_q: 4 heads/dispatch, 2 dispatches/layer (y f64 RMW traffic and
//       barrier count halved; same total proj-load count). WP in LDS
//       (node-minor mapping), G read from global (coalesced 256B/wave,
//       L1/L2-hot) so static LDS = 40608B -> exactly 4 blocks/CU.
//     Precision scheme unchanged (validated v6-v8): K-side f32, q-front f32,
//     exp->qp' f32, den/y f64. Fixed-order reductions, no atomics.

namespace {

constexpr int N    = 50000;
constexpr int C    = 64;
constexpr int H    = 8;
constexpr int HD   = 512;
constexpr int M    = 30;

constexpr int NBK  = 128;            // k_kv blocks per head -> grid 1024 (4/CU)
constexpr int NGK  = N / 16;         // 3125 groups of 16 nodes
constexpr int NBQ  = 1024;           // k_q grid (4/CU)
constexpr int NGQ8 = N / 8;          // 6250 groups of 8 nodes
constexpr int PSTR = 2016;           // f32 partial: A[0,1920) Es@1920 Sv@1950 max@2014

__device__ constexpr double DN    = 0.35355339059327373;  // 1/sqrt(sqrt(64))
__device__ constexpr double RATIO = 0.18257418583505536;  // 1/sqrt(30)
__device__ constexpr double EPSK  = 1e-6;
__device__ constexpr double EPSN  = 1e-5;

__device__ __forceinline__ void kah(double& s, double& c, double v) {
  double y = v - c; double t = s + y; c = (t - s) - y; s = t;
}

// ------ pass 0: WP[side][h] = DN * W @ P^T (f32), bp = DN * b @ P^T ----------
__global__ __launch_bounds__(256)
void k_wp(const float* __restrict__ Wk, const float* __restrict__ bk,
          const float* __restrict__ Wq, const float* __restrict__ bq,
          const float* __restrict__ P, float* __restrict__ wp,
          float* __restrict__ bp) {
  const int blk = blockIdx.x, side = blk >> 3, h = blk & 7, t = threadIdx.x;
  const float* W  = side ? Wq : Wk;
  const float* bb = side ? bq : bk;
  for (int s = t; s < 1920; s += 256) {
    const int m = s >> 6, c = s & 63;
    double a = 0.0;
    for (int d = 0; d < 64; ++d)
      a = fma((double)W[c * HD + h * 64 + d], (double)P[m * 64 + d], a);
    wp[((size_t)(side * 8 + h) * 30 + m) * 64 + c] = (float)(a * DN);
  }
  if (t < 30) {
    double a = 0.0;
    for (int d = 0; d < 64; ++d)
      a = fma((double)bb[h * 64 + d], (double)P[t * 64 + d], a);
    bp[(side * 8 + h) * 30 + t] = (float)(a * DN);
  }
}

// ------ pass 1 (f32): per-head A/Es/Sv partials + max(dd_k), 16 nodes/iter ---
__global__ __launch_bounds__(256, 4)
void k_kv(const float* __restrict__ x32,
          const float* __restrict__ Wk, const float* __restrict__ bk,
          const float* __restrict__ Wv, const float* __restrict__ bv,
          const float* __restrict__ wp, const float* __restrict__ bp,
          float* __restrict__ partial) {
  __shared__ __align__(16) float wvs[4096];       // Wv slice [c][j]
  __shared__ __align__(16) float wpk[30 * 68];    // WP_k rows, pitch 68 (17 f4)
  __shared__ __align__(16) float xs[16 * 68];     // x rows (also final scratch)
  __shared__ __align__(16) float vsd[16 * 68];    // v rows (also final scratch)
  __shared__ float kplV[30 * 16];                 // E, layout [m][node]
  __shared__ float diag[16];
  __shared__ float bpk[30];
  const int t = threadIdx.x, i0 = t >> 6, c0 = t & 63;
  const int h = blockIdx.x >> 7, b = blockIdx.x & (NBK - 1), hb = h * 64;

  for (int s = t; s < 4096; s += 256)
    wvs[s] = Wv[(s >> 6) * HD + hb + (s & 63)];
  for (int s = t; s < 1920; s += 256)
    wpk[(s >> 6) * 68 + (s & 63)] = wp[(size_t)h * 1920 + s];
  if (t < 30) bpk[t] = bp[h * 30 + t];
  const float bk0 = bk[hb + c0], bv0 = bv[hb + c0];
  float acc8[8];
#pragma unroll
  for (int k = 0; k < 8; ++k) acc8[k] = 0.0f;
  float ssv = 0.0f, ses = 0.0f, runmax = -3.0e38f;
  __syncthreads();

  for (int g = b; g < NGK; g += NBK) {
    const int n0 = g * 16;
    __syncthreads();  // protect xs/vsd/kplV reuse
#pragma unroll
    for (int u = 0; u < 4; ++u)
      xs[(i0 + 4 * u) * 68 + c0] = x32[(size_t)(n0 + i0 + 4 * u) * C + c0];
    __syncthreads();
    // k,v projection: 4 nodes/thread, float4 x reads (broadcast), 8 chains
    float ka[4], va[4];
#pragma unroll
    for (int u = 0; u < 4; ++u) { ka[u] = bk0; va[u] = bv0; }
#pragma unroll 4
    for (int c4 = 0; c4 < 16; ++c4) {
      float4 xv[4];
#pragma unroll
      for (int u = 0; u < 4; ++u)
        xv[u] = reinterpret_cast<const float4*>(xs + (i0 + 4 * u) * 68)[c4];
#pragma unroll
      for (int j = 0; j < 4; ++j) {
        const int c = c4 * 4 + j;
        const float wk_ = Wk[c * HD + hb + c0];
        const float wv_ = wvs[c * 64 + c0];
        const float xj0 = (j == 0) ? xv[0].x : (j == 1) ? xv[0].y : (j == 2) ? xv[0].z : xv[0].w;
        const float xj1 = (j == 0) ? xv[1].x : (j == 1) ? xv[1].y : (j == 2) ? xv[1].z : xv[1].w;
        const float xj2 = (j == 0) ? xv[2].x : (j == 1) ? xv[2].y : (j == 2) ? xv[2].z : xv[2].w;
        const float xj3 = (j == 0) ? xv[3].x : (j == 1) ? xv[3].y : (j == 2) ? xv[3].z : xv[3].w;
        ka[0] = fmaf(xj0, wk_, ka[0]); va[0] = fmaf(xj0, wv_, va[0]);
        ka[1] = fmaf(xj1, wk_, ka[1]); va[1] = fmaf(xj1, wv_, va[1]);
        ka[2] = fmaf(xj2, wk_, ka[2]); va[2] = fmaf(xj2, wv_, va[2]);
        ka[3] = fmaf(xj3, wk_, ka[3]); va[3] = fmaf(xj3, wv_, va[3]);
      }
    }
#pragma unroll
    for (int u = 0; u < 4; ++u) {
      vsd[(i0 + 4 * u) * 68 + c0] = va[u];
      float s = ka[u] * ka[u];
#pragma unroll
      for (int off = 32; off; off >>= 1) s += __shfl_xor(s, off, 64);
      if (c0 == 0) diag[i0 + 4 * u] = s * 0.0625f;   // DN^2/2
      ssv += va[u];
    }
    __syncthreads();
    // dd_k via WP: node-minor mapping (dm = item>>4 quasi-uniform in wave)
#pragma unroll
    for (int rep = 0; rep < 2; ++rep) {
      const int item = t + rep * 256;
      if (item < 480) {
        const int dm = item >> 4, di = item & 15;
        float a = bpk[dm];
#pragma unroll 4
        for (int c4 = 0; c4 < 16; ++c4) {
          const float4 xv = reinterpret_cast<const float4*>(xs + di * 68)[c4];
          const float4 wv = reinterpret_cast<const float4*>(wpk + dm * 68)[c4];
          a = fmaf(xv.x, wv.x, a); a = fmaf(xv.y, wv.y, a);
          a = fmaf(xv.z, wv.z, a); a = fmaf(xv.w, wv.w, a);
        }
        runmax = fmaxf(runmax, a);
        kplV[dm * 16 + di] = __expf(a - diag[di]);
      }
    }
    __syncthreads();
    if (t < 30) {  // Es[m] partial (contiguous scan)
      float gsum = 0.0f;
#pragma unroll
      for (int i = 0; i < 16; ++i) gsum += kplV[t * 16 + i];
      ses += gsum;
    }
    // A[m][c0] += E[m][i]*v[i][c0]  (kplV reads wave-uniform -> broadcast)
    float vr[16];
#pragma unroll
    for (int i = 0; i < 16; ++i) vr[i] = vsd[i * 68 + c0];
#pragma unroll
    for (int k = 0; k < 8; ++k) {
      const int s = t + (k << 8);
      if (s < 1920) {
        const int m = s >> 6;
        float gsum = acc8[k];
#pragma unroll
        for (int i = 0; i < 16; ++i)
          gsum = fmaf(kplV[m * 16 + i], vr[i], gsum);
        acc8[k] = gsum;
      }
    }
  }
  // block outputs (reuse xs / vsd as scratch)
  const size_t base = (size_t)blockIdx.x * PSTR;
  __syncthreads();
  xs[t] = ssv;
  vsd[t] = runmax;
  __syncthreads();
  if (t < 64) partial[base + 1950 + t] = xs[t] + xs[t + 64] + xs[t + 128] + xs[t + 192];
  for (int off = 128; off; off >>= 1) {
    if (t < off) vsd[t] = fmaxf(vsd[t], vsd[t + off]);
    __syncthreads();
  }
  if (t == 0) partial[base + 2014] = vsd[0];
  if (t < 30) partial[base + 1920 + t] = ses;
#pragma unroll
  for (int k = 0; k < 8; ++k) {
    const int s = t + (k << 8);
    if (s < 1920) partial[base + s] = acc8[k];
  }
}

// ------ pass 2: reduce f32 partials in f64, apply stab/eps, G = kvs@Wo ------
__global__ __launch_bounds__(256)
void k_redkv(const float* __restrict__ partial, const float* __restrict__ Wo,
             double* __restrict__ ksumg, float* __restrict__ Gg32) {
  const int h = blockIdx.x, t = threadIdx.x;
  __shared__ float red[256];
  __shared__ double svt[64];
  __shared__ double kvls[M * 64];
  __shared__ double escs;
  const size_t hb = (size_t)h * NBK;
  red[t] = (t < NBK) ? partial[(hb + t) * PSTR + 2014] : -3.0e38f;
  __syncthreads();
  for (int off = 128; off; off >>= 1) {
    if (t < off) red[t] = fmaxf(red[t], red[t + off]);
    __syncthreads();
  }
  if (t == 0) escs = exp(-(double)red[0]);
  __syncthreads();
  const double esc = escs;
  if (t < 64) {
    double s = 0.0;
    for (int b = 0; b < NBK; ++b) s += (double)partial[(hb + b) * PSTR + 1950 + t];
    svt[t] = s;
  } else if (t < 64 + M) {
    const int m = t - 64;
    double s = 0.0;
    for (int b = 0; b < NBK; ++b) s += (double)partial[(hb + b) * PSTR + 1920 + m];
    ksumg[h * M + m] = RATIO * (esc * s + EPSK * (double)N);
  }
  __syncthreads();
#pragma unroll
  for (int k = 0; k < 8; ++k) {
    const int sidx = t + (k << 8);
    if (sidx < M * 64) {
      double s = 0.0;
      for (int b = 0; b < NBK; ++b) s += (double)partial[(hb + b) * PSTR + sidx];
      kvls[sidx] = RATIO * (esc * s + EPSK * svt[sidx & 63]);
    }
  }
  __syncthreads();
#pragma unroll
  for (int k = 0; k < 8; ++k) {
    const int sidx = t + (k << 8);
    if (sidx < M * 64) {
      const int m = sidx >> 6, c = sidx & 63;
      double a = 0.0;
      for (int d = 0; d < 64; ++d)
        a = fma(kvls[m * 64 + d], (double)Wo[(h * 64 + d) * 64 + c], a);
      Gg32[(size_t)h * 1920 + sidx] = (float)a;
    }
  }
}

// ------ pass 3 (x2, 4 heads each): q-front f32 -> y += qp' @ G (f64) ---------
// MODE 0: y = bo + contrib(H0..H0+3); MODE 1: final (+leaky+colsums)
template <int MODE>
__global__ __launch_bounds__(256, 4)
void k_q(const float* __restrict__ x32,
         const float* __restrict__ Wq, const float* __restrict__ bq,
         const float* __restrict__ wp, const float* __restrict__ bp,
         const double* __restrict__ ksumg, const float* __restrict__ Gg32,
         const float* __restrict__ bo, int do_leaky, int H0,
         double* __restrict__ y, double* __restrict__ psum) {
  __shared__ __align__(16) float wpq[4 * 30 * 68];  // rows j=hh*30+m, pitch 68
  __shared__ __align__(16) float xs[8 * 68];
  __shared__ float  qpl[120 * 8];                   // [j][node]
  __shared__ float  stabd[32];                      // [hh][i]
  __shared__ float  diagd[32];                      // [i][hh]
  __shared__ double rdend[32];                      // [i][hh]
  __shared__ double ksl[120];
  __shared__ float  bpq[120];
  const int t = threadIdx.x, i0 = t >> 6, c0 = t & 63;

  for (int s = t; s < 7680; s += 256) {
    const int hh = s / 1920, r = s - hh * 1920;
    wpq[(hh * 30 + (r >> 6)) * 68 + (r & 63)] = wp[(size_t)(8 + H0 + hh) * 1920 + r];
  }
  if (t < 120) {
    ksl[t] = ksumg[H0 * 30 + t];
    bpq[t] = bp[(8 + H0) * 30 + t];
  }
  float bq4[4];
#pragma unroll
  for (int hh = 0; hh < 4; ++hh) bq4[hh] = bq[(H0 + hh) * 64 + c0];
  const double bo0 = (double)bo[c0];
  double sy = 0.0, sy2 = 0.0;
  __syncthreads();

  for (int g = blockIdx.x; g < NGQ8; g += NBQ) {
    const int n0 = g * 8;
    xs[i0 * 68 + c0]       = x32[(size_t)(n0 + i0) * C + c0];
    xs[(i0 + 4) * 68 + c0] = x32[(size_t)(n0 + i0 + 4) * C + c0];
    __syncthreads();  // S1
    // q projection (diag only): 4 heads x 2 nodes, Wq from L1/L2
    float aq[4], ar[4];
#pragma unroll
    for (int hh = 0; hh < 4; ++hh) { aq[hh] = bq4[hh]; ar[hh] = bq4[hh]; }
#pragma unroll 4
    for (int c4 = 0; c4 < 16; ++c4) {
      const float4 xa = reinterpret_cast<const float4*>(xs + i0 * 68)[c4];
      const float4 xb = reinterpret_cast<const float4*>(xs + (i0 + 4) * 68)[c4];
#pragma unroll
      for (int j = 0; j < 4; ++j) {
        const int c = c4 * 4 + j;
        const float xaj = (j == 0) ? xa.x : (j == 1) ? xa.y : (j == 2) ? xa.z : xa.w;
        const float xbj = (j == 0) ? xb.x : (j == 1) ? xb.y : (j == 2) ? xb.z : xb.w;
#pragma unroll
        for (int hh = 0; hh < 4; ++hh) {
          const float w = Wq[c * HD + (H0 + hh) * 64 + c0];
          aq[hh] = fmaf(xaj, w, aq[hh]);
          ar[hh] = fmaf(xbj, w, ar[hh]);
        }
      }
    }
#pragma unroll
    for (int hh = 0; hh < 4; ++hh) {
      float s0 = aq[hh] * aq[hh], s1 = ar[hh] * ar[hh];
#pragma unroll
      for (int off = 32; off; off >>= 1) {
        s0 += __shfl_xor(s0, off, 64);
        s1 += __shfl_xor(s1, off, 64);
      }
      if (c0 == 0) {
        diagd[i0 * 4 + hh]       = s0 * 0.0625f;
        diagd[(i0 + 4) * 4 + hh] = s1 * 0.0625f;
      }
    }
    // dd_q raw via WP, node-minor: item = j*8 + i
#pragma unroll
    for (int rep = 0; rep < 4; ++rep) {
      const int item = t + rep * 256;
      if (item < 960) {
        const int j = item >> 3, i = item & 7;
        float a = bpq[j];
#pragma unroll 4
        for (int c4 = 0; c4 < 16; ++c4) {
          const float4 xv = reinterpret_cast<const float4*>(xs + i * 68)[c4];
          const float4 wv = reinterpret_cast<const float4*>(wpq + j * 68)[c4];
          a = fmaf(xv.x, wv.x, a); a = fmaf(xv.y, wv.y, a);
          a = fmaf(xv.z, wv.z, a); a = fmaf(xv.w, wv.w, a);
        }
        qpl[item] = a;
      }
    }
    __syncthreads();  // S2
    if (t < 32) {  // stab = max over m of raw dd (hh = t>>3, i = t&7)
      const int hh = t >> 3, i = t & 7;
      float mx = qpl[(hh * 30) * 8 + i];
      for (int m = 1; m < 30; ++m) mx = fmaxf(mx, qpl[(hh * 30 + m) * 8 + i]);
      stabd[t] = mx;
    }
    __syncthreads();  // S3
#pragma unroll
    for (int rep = 0; rep < 4; ++rep) {  // qp' in place (f32)
      const int item = t + rep * 256;
      if (item < 960) {
        const int j = item >> 3, i = item & 7;
        const int hh = j / 30;
        qpl[item] = 0.18257418583505536f *
                    (__expf((qpl[item] - diagd[i * 4 + hh]) - stabd[hh * 8 + i]) + 1e-6f);
      }
    }
    __syncthreads();  // S4
    if (t < 32) {  // den f64 from the same qp'
      const int hh = t >> 3, i = t & 7;
      double den = 0.0;
      for (int m = 0; m < 30; ++m)
        den = fma((double)qpl[(hh * 30 + m) * 8 + i], ksl[hh * 30 + m], den);
      rdend[i * 4 + hh] = 1.0 / den;
    }
    __syncthreads();  // S5
    // y apply: nodes i0, i0+4 at column c0 (f64); G from global (coalesced)
    double acc_a = 0.0, acc_b = 0.0;
#pragma unroll
    for (int hh = 0; hh < 4; ++hh) {
      const float* g = Gg32 + (size_t)(H0 + hh) * 1920 + c0;
      const int jb = hh * 30;
      double sa = 0.0, sb = 0.0;
      for (int m = 0; m < 30; ++m) {
        const double gv = (double)g[m * 64];
        sa = fma((double)qpl[(jb + m) * 8 + i0], gv, sa);
        sb = fma((double)qpl[(jb + m) * 8 + i0 + 4], gv, sb);
      }
      acc_a = fma(sa, rdend[i0 * 4 + hh], acc_a);
      acc_b = fma(sb, rdend[(i0 + 4) * 4 + hh], acc_b);
    }
    const size_t ia = (size_t)(n0 + i0) * C + c0;
    const size_t ib = (size_t)(n0 + i0 + 4) * C + c0;
    if (MODE == 0) {
      y[ia] = bo0 + acc_a;
      y[ib] = bo0 + acc_b;
    } else {
      double va = y[ia] + acc_a, vb = y[ib] + acc_b;
      if (do_leaky) {
        va = (va >= 0.0) ? va : 0.01 * va;
        vb = (vb >= 0.0) ? vb : 0.01 * vb;
      }
      y[ia] = va; y[ib] = vb;
      sy += va + vb;
      sy2 = fma(va, va, sy2);
      sy2 = fma(vb, vb, sy2);
    }
    __syncthreads();  // S6: qpl reads done before next iter's overwrite
  }
  if (MODE == 1) {  // block column sums (wpq dead -> reuse as f64 scratch)
    double* red = reinterpret_cast<double*>(wpq);
    __syncthreads();
    red[t] = sy;
    __syncthreads();
    if (t < 64) psum[(size_t)blockIdx.x * 128 + t] =
        red[t] + red[t + 64] + red[t + 128] + red[t + 192];
    __syncthreads();
    red[t] = sy2;
    __syncthreads();
    if (t < 64) psum[(size_t)blockIdx.x * 128 + 64 + t] =
        red[t] + red[t + 64] + red[t + 128] + red[t + 192];
  }
}

// ------ graph-norm parameters ------------------------------------------------
__global__ void k_norm_params(const double* __restrict__ psum,
                              const float* __restrict__ gamma, const float* __restrict__ beta,
                              const float* __restrict__ alpha, double* __restrict__ nparam) {
  const int t = threadIdx.x;
  __shared__ double m1l[64], m2l[64];
  if (t < 64) {
    double s = 0, c = 0;
    for (int b = 0; b < NBQ; ++b) kah(s, c, psum[(size_t)b * 128 + t]);
    m1l[t] = s - c;
  } else if (t < 128) {
    const int ci = t - 64;
    double s = 0, c = 0;
    for (int b = 0; b < NBQ; ++b) kah(s, c, psum[(size_t)b * 128 + 64 + ci]);
    m2l[ci] = s - c;
  }
  __syncthreads();
  if (t < 64) {
    const double mu = m1l[t] / (double)N;
    const double m2 = m2l[t] / (double)N;
    const double al = (double)alpha[t];
    double var = m2 - (2.0 * al - al * al) * mu * mu;
    if (var < 0.0) var = 0.0;
    nparam[t]       = al * mu;
    nparam[64 + t]  = (double)gamma[t] / sqrt(var + EPSN);
    nparam[128 + t] = (double)beta[t];
  }
}

// ------ normalize y -> f32 (next-layer x32, or final output) -----------------
__global__ void k_cast(const double* __restrict__ yv, const double* __restrict__ nparam,
                       float* __restrict__ dst) {
  const int total = N * C;
  for (int i = blockIdx.x * blockDim.x + threadIdx.x; i < total; i += gridDim.x * blockDim.x) {
    const int c = i & 63;
    dst[i] = (float)((yv[i] - nparam[c]) * nparam[64 + c] + nparam[128 + c]);
  }
}

}  // namespace

extern "C" void kernel_launch(void* const* d_in, const int* in_sizes, int n_in,
                              void* d_out, int out_size, void* d_ws, size_t ws_size,
                              hipStream_t stream) {
  const float* patch = (const float*)d_in[0];
  // d_in[1] edge_index, d_in[2] edge_attr: unused by the reference
  const float* Wq = (const float*)d_in[3];
  const float* Wk = (const float*)d_in[4];
  const float* Wv = (const float*)d_in[5];
  const float* Wo = (const float*)d_in[6];
  const float* bq = (const float*)d_in[7];
  const float* bk = (const float*)d_in[8];
  const float* bv = (const float*)d_in[9];
  const float* bo = (const float*)d_in[10];
  const float* P  = (const float*)d_in[11];
  const float* ga = (const float*)d_in[12];
  const float* be = (const float*)d_in[13];
  const float* al = (const float*)d_in[14];
  float* out = (float*)d_out;

  // workspace (~48 MB): f64 first (alignment), then f32
  char* wsb = (char*)d_ws;
  double* y      = (double*)wsb;   wsb += (size_t)N * C * 8;               // 25.6MB
  double* psum   = (double*)wsb;   wsb += (size_t)NBQ * 128 * 8;           // 1.0MB
  double* nparam = (double*)wsb;   wsb += 192 * 8;
  double* ksumg  = (double*)wsb;   wsb += (size_t)H * M * 8;
  float*  x32    = (float*)wsb;    wsb += (size_t)N * C * 4;               // 12.8MB
  float*  partial= (float*)wsb;    wsb += (size_t)(H * NBK) * PSTR * 4;    // 8.3MB
  float*  G32    = (float*)wsb;    wsb += (size_t)H * M * 64 * 4;          // 61KB
  float*  wpf    = (float*)wsb;    wsb += (size_t)2 * H * M * 64 * 4;      // 123KB
  float*  bpf    = (float*)wsb;    wsb += (size_t)2 * H * M * 4;

  for (int L = 0; L < 3; ++L) {
    const float* wq  = Wq + (size_t)L * C * HD;
    const float* wk  = Wk + (size_t)L * C * HD;
    const float* wv  = Wv + (size_t)L * C * HD;
    const float* wo  = Wo + (size_t)L * HD * C;
    const float* bq_ = bq + (size_t)L * HD;
    const float* bk_ = bk + (size_t)L * HD;
    const float* bv_ = bv + (size_t)L * HD;
    const float* bo_ = bo + (size_t)L * C;
    const float* p   = P  + (size_t)L * M * C;
    const int leaky = (L < 2) ? 1 : 0;
    const float* xcur = (L == 0) ? patch : x32;

    k_wp<<<16, 256, 0, stream>>>(wk, bk_, wq, bq_, p, wpf, bpf);
    k_kv<<<H * NBK, 256, 0, stream>>>(xcur, wk, bk_, wv, bv_, wpf, bpf, partial);
    k_redkv<<<H, 256, 0, stream>>>(partial, wo, ksumg, G32);

    k_q<0><<<NBQ, 256, 0, stream>>>(xcur, wq, bq_, wpf, bpf, ksumg, G32, bo_,
                                    leaky, 0, y, psum);
    k_q<1><<<NBQ, 256, 0, stream>>>(xcur, wq, bq_, wpf, bpf, ksumg, G32, bo_,
                                    leaky, 4, y, psum);

    k_norm_params<<<1, 128, 0, stream>>>(psum, ga + (size_t)L * C, be + (size_t)L * C,
                                         al + (size_t)L * C, nparam);
    k_cast<<<512, 256, 0, stream>>>(y, nparam, (L < 2) ? x32 : out);
  }
}

// Round 12
// 2362.954 us; speedup vs baseline: 2.0310x; 2.0310x over previous
//
#include <hip/hip_runtime.h>
#include <math.h>

// NodeformerProcessor: 3x (nodeformer_conv -> [leaky] -> graph_norm).
// v10: v9's k_kv (bank-conflict-free, kept) + k_q reverted to v8's proven
//      2-head/dispatch structure (WP + G LDS-resident, Wq 2-head slice =
//      32KB L1-resident) with v9's node-minor dd mapping (wave-broadcast
//      LDS rows, conflict-free). v9's 4-head k_q streamed 680MB/dispatch
//      from HBM (64KB Wq slice + global G thrashed by x/y streams).
//      LDS 38.8KB -> exactly 4 blocks/CU. Precision scheme validated
//      v6-v9: K-side f32, q-front f32, qp' f32, den/y f64. Fixed-order
//      reductions, no atomics.

namespace {

constexpr int N    = 50000;
constexpr int C    = 64;
constexpr int H    = 8;
constexpr int HD   = 512;
constexpr int M    = 30;

constexpr int NBK  = 128;            // k_kv blocks per head -> grid 1024 (4/CU)
constexpr int NGK  = N / 16;         // 3125 groups of 16 nodes
constexpr int NBQ  = 1024;           // k_q grid (4/CU)
constexpr int NGQ8 = N / 8;          // 6250 groups of 8 nodes
constexpr int PSTR = 2016;           // f32 partial: A[0,1920) Es@1920 Sv@1950 max@2014

__device__ constexpr double DN    = 0.35355339059327373;  // 1/sqrt(sqrt(64))
__device__ constexpr double RATIO = 0.18257418583505536;  // 1/sqrt(30)
__device__ constexpr double EPSK  = 1e-6;
__device__ constexpr double EPSN  = 1e-5;

__device__ __forceinline__ void kah(double& s, double& c, double v) {
  double y = v - c; double t = s + y; c = (t - s) - y; s = t;
}

// ------ pass 0: WP[side][h] = DN * W @ P^T (f32), bp = DN * b @ P^T ----------
__global__ __launch_bounds__(256)
void k_wp(const float* __restrict__ Wk, const float* __restrict__ bk,
          const float* __restrict__ Wq, const float* __restrict__ bq,
          const float* __restrict__ P, float* __restrict__ wp,
          float* __restrict__ bp) {
  const int blk = blockIdx.x, side = blk >> 3, h = blk & 7, t = threadIdx.x;
  const float* W  = side ? Wq : Wk;
  const float* bb = side ? bq : bk;
  for (int s = t; s < 1920; s += 256) {
    const int m = s >> 6, c = s & 63;
    double a = 0.0;
    for (int d = 0; d < 64; ++d)
      a = fma((double)W[c * HD + h * 64 + d], (double)P[m * 64 + d], a);
    wp[((size_t)(side * 8 + h) * 30 + m) * 64 + c] = (float)(a * DN);
  }
  if (t < 30) {
    double a = 0.0;
    for (int d = 0; d < 64; ++d)
      a = fma((double)bb[h * 64 + d], (double)P[t * 64 + d], a);
    bp[(side * 8 + h) * 30 + t] = (float)(a * DN);
  }
}

// ------ pass 1 (f32): per-head A/Es/Sv partials + max(dd_k), 16 nodes/iter ---
__global__ __launch_bounds__(256, 4)
void k_kv(const float* __restrict__ x32,
          const float* __restrict__ Wk, const float* __restrict__ bk,
          const float* __restrict__ Wv, const float* __restrict__ bv,
          const float* __restrict__ wp, const float* __restrict__ bp,
          float* __restrict__ partial) {
  __shared__ __align__(16) float wvs[4096];       // Wv slice [c][j]
  __shared__ __align__(16) float wpk[30 * 68];    // WP_k rows, pitch 68 (17 f4)
  __shared__ __align__(16) float xs[16 * 68];     // x rows (also final scratch)
  __shared__ __align__(16) float vsd[16 * 68];    // v rows (also final scratch)
  __shared__ float kplV[30 * 16];                 // E, layout [m][node]
  __shared__ float diag[16];
  __shared__ float bpk[30];
  const int t = threadIdx.x, i0 = t >> 6, c0 = t & 63;
  const int h = blockIdx.x >> 7, b = blockIdx.x & (NBK - 1), hb = h * 64;

  for (int s = t; s < 4096; s += 256)
    wvs[s] = Wv[(s >> 6) * HD + hb + (s & 63)];
  for (int s = t; s < 1920; s += 256)
    wpk[(s >> 6) * 68 + (s & 63)] = wp[(size_t)h * 1920 + s];
  if (t < 30) bpk[t] = bp[h * 30 + t];
  const float bk0 = bk[hb + c0], bv0 = bv[hb + c0];
  float acc8[8];
#pragma unroll
  for (int k = 0; k < 8; ++k) acc8[k] = 0.0f;
  float ssv = 0.0f, ses = 0.0f, runmax = -3.0e38f;
  __syncthreads();

  for (int g = b; g < NGK; g += NBK) {
    const int n0 = g * 16;
    __syncthreads();  // protect xs/vsd/kplV reuse
#pragma unroll
    for (int u = 0; u < 4; ++u)
      xs[(i0 + 4 * u) * 68 + c0] = x32[(size_t)(n0 + i0 + 4 * u) * C + c0];
    __syncthreads();
    // k,v projection: 4 nodes/thread, float4 x reads (broadcast), 8 chains
    float ka[4], va[4];
#pragma unroll
    for (int u = 0; u < 4; ++u) { ka[u] = bk0; va[u] = bv0; }
#pragma unroll 4
    for (int c4 = 0; c4 < 16; ++c4) {
      float4 xv[4];
#pragma unroll
      for (int u = 0; u < 4; ++u)
        xv[u] = reinterpret_cast<const float4*>(xs + (i0 + 4 * u) * 68)[c4];
#pragma unroll
      for (int j = 0; j < 4; ++j) {
        const int c = c4 * 4 + j;
        const float wk_ = Wk[c * HD + hb + c0];
        const float wv_ = wvs[c * 64 + c0];
        const float xj0 = (j == 0) ? xv[0].x : (j == 1) ? xv[0].y : (j == 2) ? xv[0].z : xv[0].w;
        const float xj1 = (j == 0) ? xv[1].x : (j == 1) ? xv[1].y : (j == 2) ? xv[1].z : xv[1].w;
        const float xj2 = (j == 0) ? xv[2].x : (j == 1) ? xv[2].y : (j == 2) ? xv[2].z : xv[2].w;
        const float xj3 = (j == 0) ? xv[3].x : (j == 1) ? xv[3].y : (j == 2) ? xv[3].z : xv[3].w;
        ka[0] = fmaf(xj0, wk_, ka[0]); va[0] = fmaf(xj0, wv_, va[0]);
        ka[1] = fmaf(xj1, wk_, ka[1]); va[1] = fmaf(xj1, wv_, va[1]);
        ka[2] = fmaf(xj2, wk_, ka[2]); va[2] = fmaf(xj2, wv_, va[2]);
        ka[3] = fmaf(xj3, wk_, ka[3]); va[3] = fmaf(xj3, wv_, va[3]);
      }
    }
#pragma unroll
    for (int u = 0; u < 4; ++u) {
      vsd[(i0 + 4 * u) * 68 + c0] = va[u];
      float s = ka[u] * ka[u];
#pragma unroll
      for (int off = 32; off; off >>= 1) s += __shfl_xor(s, off, 64);
      if (c0 == 0) diag[i0 + 4 * u] = s * 0.0625f;   // DN^2/2
      ssv += va[u];
    }
    __syncthreads();
    // dd_k via WP: node-minor mapping (dm = item>>4 quasi-uniform in wave)
#pragma unroll
    for (int rep = 0; rep < 2; ++rep) {
      const int item = t + rep * 256;
      if (item < 480) {
        const int dm = item >> 4, di = item & 15;
        float a = bpk[dm];
#pragma unroll 4
        for (int c4 = 0; c4 < 16; ++c4) {
          const float4 xv = reinterpret_cast<const float4*>(xs + di * 68)[c4];
          const float4 wv = reinterpret_cast<const float4*>(wpk + dm * 68)[c4];
          a = fmaf(xv.x, wv.x, a); a = fmaf(xv.y, wv.y, a);
          a = fmaf(xv.z, wv.z, a); a = fmaf(xv.w, wv.w, a);
        }
        runmax = fmaxf(runmax, a);
        kplV[dm * 16 + di] = __expf(a - diag[di]);
      }
    }
    __syncthreads();
    if (t < 30) {  // Es[m] partial (contiguous scan)
      float gsum = 0.0f;
#pragma unroll
      for (int i = 0; i < 16; ++i) gsum += kplV[t * 16 + i];
      ses += gsum;
    }
    // A[m][c0] += E[m][i]*v[i][c0]  (kplV reads wave-uniform -> broadcast)
    float vr[16];
#pragma unroll
    for (int i = 0; i < 16; ++i) vr[i] = vsd[i * 68 + c0];
#pragma unroll
    for (int k = 0; k < 8; ++k) {
      const int s = t + (k << 8);
      if (s < 1920) {
        const int m = s >> 6;
        float gsum = acc8[k];
#pragma unroll
        for (int i = 0; i < 16; ++i)
          gsum = fmaf(kplV[m * 16 + i], vr[i], gsum);
        acc8[k] = gsum;
      }
    }
  }
  // block outputs (reuse xs / vsd as scratch)
  const size_t base = (size_t)blockIdx.x * PSTR;
  __syncthreads();
  xs[t] = ssv;
  vsd[t] = runmax;
  __syncthreads();
  if (t < 64) partial[base + 1950 + t] = xs[t] + xs[t + 64] + xs[t + 128] + xs[t + 192];
  for (int off = 128; off; off >>= 1) {
    if (t < off) vsd[t] = fmaxf(vsd[t], vsd[t + off]);
    __syncthreads();
  }
  if (t == 0) partial[base + 2014] = vsd[0];
  if (t < 30) partial[base + 1920 + t] = ses;
#pragma unroll
  for (int k = 0; k < 8; ++k) {
    const int s = t + (k << 8);
    if (s < 1920) partial[base + s] = acc8[k];
  }
}

// ------ pass 2: reduce f32 partials in f64, apply stab/eps, G = kvs@Wo ------
__global__ __launch_bounds__(256)
void k_redkv(const float* __restrict__ partial, const float* __restrict__ Wo,
             double* __restrict__ ksumg, float* __restrict__ Gg32) {
  const int h = blockIdx.x, t = threadIdx.x;
  __shared__ float red[256];
  __shared__ double svt[64];
  __shared__ double kvls[M * 64];
  __shared__ double escs;
  const size_t hb = (size_t)h * NBK;
  red[t] = (t < NBK) ? partial[(hb + t) * PSTR + 2014] : -3.0e38f;
  __syncthreads();
  for (int off = 128; off; off >>= 1) {
    if (t < off) red[t] = fmaxf(red[t], red[t + off]);
    __syncthreads();
  }
  if (t == 0) escs = exp(-(double)red[0]);
  __syncthreads();
  const double esc = escs;
  if (t < 64) {
    double s = 0.0;
    for (int b = 0; b < NBK; ++b) s += (double)partial[(hb + b) * PSTR + 1950 + t];
    svt[t] = s;
  } else if (t < 64 + M) {
    const int m = t - 64;
    double s = 0.0;
    for (int b = 0; b < NBK; ++b) s += (double)partial[(hb + b) * PSTR + 1920 + m];
    ksumg[h * M + m] = RATIO * (esc * s + EPSK * (double)N);
  }
  __syncthreads();
#pragma unroll
  for (int k = 0; k < 8; ++k) {
    const int sidx = t + (k << 8);
    if (sidx < M * 64) {
      double s = 0.0;
      for (int b = 0; b < NBK; ++b) s += (double)partial[(hb + b) * PSTR + sidx];
      kvls[sidx] = RATIO * (esc * s + EPSK * svt[sidx & 63]);
    }
  }
  __syncthreads();
#pragma unroll
  for (int k = 0; k < 8; ++k) {
    const int sidx = t + (k << 8);
    if (sidx < M * 64) {
      const int m = sidx >> 6, c = sidx & 63;
      double a = 0.0;
      for (int d = 0; d < 64; ++d)
        a = fma(kvls[m * 64 + d], (double)Wo[(h * 64 + d) * 64 + c], a);
      Gg32[(size_t)h * 1920 + sidx] = (float)a;
    }
  }
}

// ------ pass 3 (x4, 2 heads each): q-front f32 -> y += qp' @ G (f64) ---------
// MODE 0: y = bo + contrib; MODE 1: y += contrib; MODE 2: final (+leaky+colsums)
template <int MODE>
__global__ __launch_bounds__(256, 4)
void k_q(const float* __restrict__ x32,
         const float* __restrict__ Wq, const float* __restrict__ bq,
         const float* __restrict__ wp, const float* __restrict__ bp,
         const double* __restrict__ ksumg, const float* __restrict__ Gg32,
         const float* __restrict__ bo, int do_leaky, int H0,
         double* __restrict__ y, double* __restrict__ psum) {
  __shared__ __align__(16) float wpq[60 * 68];   // rows j = hh*30+m, pitch 68
  __shared__ float Gl[2][1920];
  __shared__ __align__(16) float xs[8 * 68];
  __shared__ float  qpl[60 * 8];                 // [j][i] node-minor
  __shared__ float  stabd[16];                   // [hh][i]
  __shared__ float  diagd[16];                   // [i][hh]
  __shared__ double rdend[16];                   // [i][hh]
  __shared__ double ksl[60];
  __shared__ float  bpq[60];
  __shared__ double red[256];
  const int t = threadIdx.x, i0 = t >> 6, c0 = t & 63;

  for (int s = t; s < 3840; s += 256) {
    const int hh = s / 1920, r = s - hh * 1920;
    wpq[(hh * 30 + (r >> 6)) * 68 + (r & 63)] = wp[(size_t)(8 + H0 + hh) * 1920 + r];
    Gl[hh][r] = Gg32[(size_t)(H0 + hh) * 1920 + r];
  }
  if (t < 60) {
    ksl[t] = ksumg[H0 * 30 + t];
    bpq[t] = bp[(8 + H0) * 30 + t];
  }
  const float bqA = bq[H0 * 64 + c0];
  const float bqB = bq[H0 * 64 + 64 + c0];
  const double bo0 = (double)bo[c0];
  double sy = 0.0, sy2 = 0.0;
  __syncthreads();

  for (int g = blockIdx.x; g < NGQ8; g += NBQ) {
    const int n0 = g * 8;
    xs[i0 * 68 + c0]       = x32[(size_t)(n0 + i0) * C + c0];
    xs[(i0 + 4) * 68 + c0] = x32[(size_t)(n0 + i0 + 4) * C + c0];
    __syncthreads();  // S1 (also fences prev iter's qpl reads: all xs reads < S2)
    // q projection (diag only): 2 heads x 2 nodes, Wq slice (32KB) L1-resident
    float aq0 = bqA, aq1 = bqB, aq2 = bqA, aq3 = bqB;
#pragma unroll 4
    for (int c4 = 0; c4 < 16; ++c4) {
      const float4 xa = reinterpret_cast<const float4*>(xs + i0 * 68)[c4];
      const float4 xb = reinterpret_cast<const float4*>(xs + (i0 + 4) * 68)[c4];
#pragma unroll
      for (int j = 0; j < 4; ++j) {
        const int c = c4 * 4 + j;
        const float wA = Wq[c * HD + H0 * 64 + c0];
        const float wB = Wq[c * HD + H0 * 64 + 64 + c0];
        const float xaj = (j == 0) ? xa.x : (j == 1) ? xa.y : (j == 2) ? xa.z : xa.w;
        const float xbj = (j == 0) ? xb.x : (j == 1) ? xb.y : (j == 2) ? xb.z : xb.w;
        aq0 = fmaf(xaj, wA, aq0); aq1 = fmaf(xaj, wB, aq1);
        aq2 = fmaf(xbj, wA, aq2); aq3 = fmaf(xbj, wB, aq3);
      }
    }
    {
      float s0 = aq0 * aq0, s1 = aq1 * aq1, s2 = aq2 * aq2, s3 = aq3 * aq3;
#pragma unroll
      for (int off = 32; off; off >>= 1) {
        s0 += __shfl_xor(s0, off, 64); s1 += __shfl_xor(s1, off, 64);
        s2 += __shfl_xor(s2, off, 64); s3 += __shfl_xor(s3, off, 64);
      }
      if (c0 == 0) {
        diagd[i0 * 2]           = s0 * 0.0625f;   // DN^2/2
        diagd[i0 * 2 + 1]       = s1 * 0.0625f;
        diagd[(i0 + 4) * 2]     = s2 * 0.0625f;
        diagd[(i0 + 4) * 2 + 1] = s3 * 0.0625f;
      }
    }
    // dd_q raw via WP, node-minor: item = j*8 + i (rows wave-broadcast)
#pragma unroll
    for (int rep = 0; rep < 2; ++rep) {
      const int item = t + rep * 256;
      if (item < 480) {
        const int j = item >> 3, i = item & 7;
        float a = bpq[j];
#pragma unroll 4
        for (int c4 = 0; c4 < 16; ++c4) {
          const float4 xv = reinterpret_cast<const float4*>(xs + i * 68)[c4];
          const float4 wv = reinterpret_cast<const float4*>(wpq + j * 68)[c4];
          a = fmaf(xv.x, wv.x, a); a = fmaf(xv.y, wv.y, a);
          a = fmaf(xv.z, wv.z, a); a = fmaf(xv.w, wv.w, a);
        }
        qpl[item] = a;
      }
    }
    __syncthreads();  // S2
    if (t < 16) {  // stab = max over m of raw dd (hh = t>>3, i = t&7)
      const int hh = t >> 3, i = t & 7;
      float mx = qpl[(hh * 30) * 8 + i];
      for (int m = 1; m < 30; ++m) mx = fmaxf(mx, qpl[(hh * 30 + m) * 8 + i]);
      stabd[t] = mx;
    }
    __syncthreads();  // S3
#pragma unroll
    for (int rep = 0; rep < 2; ++rep) {  // qp' in place (f32)
      const int item = t + rep * 256;
      if (item < 480) {
        const int j = item >> 3, i = item & 7;
        const int hh = (j >= 30) ? 1 : 0;
        qpl[item] = 0.18257418583505536f *
                    (__expf((qpl[item] - diagd[i * 2 + hh]) - stabd[hh * 8 + i]) + 1e-6f);
      }
    }
    __syncthreads();  // S4
    if (t < 16) {  // den f64 from the same qp'
      const int hh = t >> 3, i = t & 7;
      double den = 0.0;
      for (int m = 0; m < 30; ++m)
        den = fma((double)qpl[(hh * 30 + m) * 8 + i], ksl[hh * 30 + m], den);
      rdend[i * 2 + hh] = 1.0 / den;
    }
    __syncthreads();  // S5
    // y apply: nodes i0, i0+4 at column c0 (f64); G from LDS
    double acc_a = 0.0, acc_b = 0.0;
#pragma unroll
    for (int hh = 0; hh < 2; ++hh) {
      const float* g = Gl[hh] + c0;
      const int jb = hh * 30;
      double sa = 0.0, sb = 0.0;
      for (int m = 0; m < 30; ++m) {
        const double gv = (double)g[m * 64];
        sa = fma((double)qpl[(jb + m) * 8 + i0], gv, sa);
        sb = fma((double)qpl[(jb + m) * 8 + i0 + 4], gv, sb);
      }
      acc_a = fma(sa, rdend[i0 * 2 + hh], acc_a);
      acc_b = fma(sb, rdend[(i0 + 4) * 2 + hh], acc_b);
    }
    const size_t ia = (size_t)(n0 + i0) * C + c0;
    const size_t ib = (size_t)(n0 + i0 + 4) * C + c0;
    if (MODE == 0) {
      y[ia] = bo0 + acc_a;
      y[ib] = bo0 + acc_b;
    } else if (MODE == 1) {
      y[ia] += acc_a;
      y[ib] += acc_b;
    } else {
      double va = y[ia] + acc_a, vb = y[ib] + acc_b;
      if (do_leaky) {
        va = (va >= 0.0) ? va : 0.01 * va;
        vb = (vb >= 0.0) ? vb : 0.01 * vb;
      }
      y[ia] = va; y[ib] = vb;
      sy += va + vb;
      sy2 = fma(va, va, sy2);
      sy2 = fma(vb, vb, sy2);
    }
    // no trailing barrier: next iter's qpl writes are gated by S1
  }
  if (MODE == 2) {  // block column sums
    __syncthreads();
    red[t] = sy;
    __syncthreads();
    if (t < 64) psum[(size_t)blockIdx.x * 128 + t] =
        red[t] + red[t + 64] + red[t + 128] + red[t + 192];
    __syncthreads();
    red[t] = sy2;
    __syncthreads();
    if (t < 64) psum[(size_t)blockIdx.x * 128 + 64 + t] =
        red[t] + red[t + 64] + red[t + 128] + red[t + 192];
  }
}

// ------ graph-norm parameters ------------------------------------------------
__global__ void k_norm_params(const double* __restrict__ psum,
                              const float* __restrict__ gamma, const float* __restrict__ beta,
                              const float* __restrict__ alpha, double* __restrict__ nparam) {
  const int t = threadIdx.x;
  __shared__ double m1l[64], m2l[64];
  if (t < 64) {
    double s = 0, c = 0;
    for (int b = 0; b < NBQ; ++b) kah(s, c, psum[(size_t)b * 128 + t]);
    m1l[t] = s - c;
  } else if (t < 128) {
    const int ci = t - 64;
    double s = 0, c = 0;
    for (int b = 0; b < NBQ; ++b) kah(s, c, psum[(size_t)b * 128 + 64 + ci]);
    m2l[ci] = s - c;
  }
  __syncthreads();
  if (t < 64) {
    const double mu = m1l[t] / (double)N;
    const double m2 = m2l[t] / (double)N;
    const double al = (double)alpha[t];
    double var = m2 - (2.0 * al - al * al) * mu * mu;
    if (var < 0.0) var = 0.0;
    nparam[t]       = al * mu;
    nparam[64 + t]  = (double)gamma[t] / sqrt(var + EPSN);
    nparam[128 + t] = (double)beta[t];
  }
}

// ------ normalize y -> f32 (next-layer x32, or final output) -----------------
__global__ void k_cast(const double* __restrict__ yv, const double* __restrict__ nparam,
                       float* __restrict__ dst) {
  const int total = N * C;
  for (int i = blockIdx.x * blockDim.x + threadIdx.x; i < total; i += gridDim.x * blockDim.x) {
    const int c = i & 63;
    dst[i] = (float)((yv[i] - nparam[c]) * nparam[64 + c] + nparam[128 + c]);
  }
}

}  // namespace

extern "C" void kernel_launch(void* const* d_in, const int* in_sizes, int n_in,
                              void* d_out, int out_size, void* d_ws, size_t ws_size,
                              hipStream_t stream) {
  const float* patch = (const float*)d_in[0];
  // d_in[1] edge_index, d_in[2] edge_attr: unused by the reference
  const float* Wq = (const float*)d_in[3];
  const float* Wk = (const float*)d_in[4];
  const float* Wv = (const float*)d_in[5];
  const float* Wo = (const float*)d_in[6];
  const float* bq = (const float*)d_in[7];
  const float* bk = (const float*)d_in[8];
  const float* bv = (const float*)d_in[9];
  const float* bo = (const float*)d_in[10];
  const float* P  = (const float*)d_in[11];
  const float* ga = (const float*)d_in[12];
  const float* be = (const float*)d_in[13];
  const float* al = (const float*)d_in[14];
  float* out = (float*)d_out;

  // workspace (~48 MB): f64 first (alignment), then f32
  char* wsb = (char*)d_ws;
  double* y      = (double*)wsb;   wsb += (size_t)N * C * 8;               // 25.6MB
  double* psum   = (double*)wsb;   wsb += (size_t)NBQ * 128 * 8;           // 1.0MB
  double* nparam = (double*)wsb;   wsb += 192 * 8;
  double* ksumg  = (double*)wsb;   wsb += (size_t)H * M * 8;
  float*  x32    = (float*)wsb;    wsb += (size_t)N * C * 4;               // 12.8MB
  float*  partial= (float*)wsb;    wsb += (size_t)(H * NBK) * PSTR * 4;    // 8.3MB
  float*  G32    = (float*)wsb;    wsb += (size_t)H * M * 64 * 4;          // 61KB
  float*  wpf    = (float*)wsb;    wsb += (size_t)2 * H * M * 64 * 4;      // 123KB
  float*  bpf    = (float*)wsb;    wsb += (size_t)2 * H * M * 4;

  for (int L = 0; L < 3; ++L) {
    const float* wq  = Wq + (size_t)L * C * HD;
    const float* wk  = Wk + (size_t)L * C * HD;
    const float* wv  = Wv + (size_t)L * C * HD;
    const float* wo  = Wo + (size_t)L * HD * C;
    const float* bq_ = bq + (size_t)L * HD;
    const float* bk_ = bk + (size_t)L * HD;
    const float* bv_ = bv + (size_t)L * HD;
    const float* bo_ = bo + (size_t)L * C;
    const float* p   = P  + (size_t)L * M * C;
    const int leaky = (L < 2) ? 1 : 0;
    const float* xcur = (L == 0) ? patch : x32;

    k_wp<<<16, 256, 0, stream>>>(wk, bk_, wq, bq_, p, wpf, bpf);
    k_kv<<<H * NBK, 256, 0, stream>>>(xcur, wk, bk_, wv, bv_, wpf, bpf, partial);
    k_redkv<<<H, 256, 0, stream>>>(partial, wo, ksumg, G32);

    k_q<0><<<NBQ, 256, 0, stream>>>(xcur, wq, bq_, wpf, bpf, ksumg, G32, bo_,
                                    leaky, 0, y, psum);
    k_q<1><<<NBQ, 256, 0, stream>>>(xcur, wq, bq_, wpf, bpf, ksumg, G32, bo_,
                                    leaky, 2, y, psum);
    k_q<1><<<NBQ, 256, 0, stream>>>(xcur, wq, bq_, wpf, bpf, ksumg, G32, bo_,
                                    leaky, 4, y, psum);
    k_q<2><<<NBQ, 256, 0, stream>>>(xcur, wq, bq_, wpf, bpf, ksumg, G32, bo_,
                                    leaky, 6, y, psum);

    k_norm_params<<<1, 128, 0, stream>>>(psum, ga + (size_t)L * C, be + (size_t)L * C,
                                         al + (size_t)L * C, nparam);
    k_cast<<<512, 256, 0, stream>>>(y, nparam, (L < 2) ? x32 : out);
  }
}